// Round 8
// baseline (529.846 us; speedup 1.0000x reference)
//
#include <hip/hip_runtime.h>
#include <hip/hip_bf16.h>
#include <hip/hip_fp16.h>

// Problem constants (B=2, T=2048, DIM=1024, FF=4096, E=8, TOPK=2)
#define NTOK 4096
#define DIM 1024
#define FF 4096
#define NE 8
#define NSLOT 8192   // NTOK * TOPK

typedef _Float16 half8 __attribute__((ext_vector_type(8)));
typedef _Float16 half4 __attribute__((ext_vector_type(4)));
typedef float floatx4 __attribute__((ext_vector_type(4)));

__device__ __forceinline__ float gelu_exact(float x) {
    return 0.5f * x * (1.0f + erff(x * 0.70710678118654752f));
}

__device__ __forceinline__ void gl_lds16(const void* g, void* l) {
    __builtin_amdgcn_global_load_lds(
        (const __attribute__((address_space(1))) void*)g,
        (__attribute__((address_space(3))) void*)l, 16, 0, 0);
}

// ---------------- 128r x 64c transpose tile: src fp32 [R][C] -> dst fp16 [C][R] ----------------
// LDS float [128][64], XOR-swizzled col: c_phys = c ^ (((r>>3)&15)<<2).
// Read banks: 32 distinct / 2 lanes each (conflict-free); store 2-way (free).
__device__ __forceinline__ void transpose_tile128(const float* __restrict__ s,
                                                  _Float16* __restrict__ d,
                                                  int R, int C, int r0, int c0,
                                                  char* smem) {
    float* t = (float*)smem;   // [128][64] swizzled
    int tid = threadIdx.x;
    int rr = tid >> 4, cc = (tid & 15) * 4;
#pragma unroll
    for (int i = 0; i < 8; ++i) {
        int r = rr + i * 16;
        float4 v = *(const float4*)(s + (size_t)(r0 + r) * C + c0 + cc);
        *(float4*)(t + r * 64 + (cc ^ (((r >> 3) & 15) << 2))) = v;
    }
    __syncthreads();
#pragma unroll
    for (int j = 0; j < 4; ++j) {
        int chunk = j * 256 + tid;
        int fr = chunk >> 4, ch = chunk & 15;
        half8 v;
#pragma unroll
        for (int u = 0; u < 8; ++u)
            v[u] = (_Float16)t[(ch * 8 + u) * 64 + (fr ^ (ch << 2))];
        *(half8*)(d + (size_t)(c0 + fr) * R + r0 + ch * 8) = v;
    }
}

// ---------------- k_prep: fused W1T + convert_x + router + (flag-gated) prefix/slots ----------------
// grid 7*1024+1. bid<7168: q=bid/7, r=bid%7: r<4 -> W1T tile; r in {4,5} -> convert_x; r=6 -> router.
// bid==7168: spin for router completion, then prefix + tmaps + slots.
__global__ __launch_bounds__(256) void k_prep(
    const float* __restrict__ x,
    const float* __restrict__ Wr,
    const float* __restrict__ W1,
    _Float16* __restrict__ w1t,
    _Float16* __restrict__ xh,
    int* __restrict__ counts,          // [0..7]=counts, [8]=rdone
    int* __restrict__ offs,
    int* __restrict__ tmap256,
    int* __restrict__ tmap128,
    int* __restrict__ tok_e,
    float* __restrict__ tok_w,
    int* __restrict__ tok_pos,
    int* __restrict__ tok_slot,
    int* __restrict__ list_tok) {
    __shared__ char smem[32768];
    int bid = blockIdx.x;
    int tid = threadIdx.x;
    int* rdone = counts + 8;

    if (bid == 7168) {
        // ---- prefix + slots consumer ----
        if (tid == 0) {
            while (__hip_atomic_load(rdone, __ATOMIC_ACQUIRE, __HIP_MEMORY_SCOPE_AGENT) < 1024)
                __builtin_amdgcn_s_sleep(8);
        }
        __syncthreads();
        (void)__hip_atomic_load(rdone, __ATOMIC_ACQUIRE, __HIP_MEMORY_SCOPE_AGENT);
        int* soffs = (int*)smem;
        if (tid == 0) {
            int s = 0, n2 = 0, n1 = 0;
            for (int e = 0; e < NE; ++e) {
                offs[e] = s; soffs[e] = s;
                int c = counts[e];
                for (int mt = 0; mt * 256 < c; ++mt) tmap256[1 + n2++] = (e << 16) | mt;
                for (int mt = 0; mt * 128 < c; ++mt) tmap128[1 + n1++] = (e << 16) | mt;
                s += c;
            }
            offs[NE] = s;
            tmap256[0] = n2;
            tmap128[0] = n1;
        }
        __syncthreads();
        for (int idx = tid; idx < NSLOT; idx += 256) {
            int e = tok_e[idx];
            int slot = soffs[e] + tok_pos[idx];
            tok_slot[idx] = slot;
            list_tok[slot] = idx >> 1;
        }
        return;
    }

    int q = bid / 7, r = bid % 7;
    if (r < 4) {
        // W1 [E][DIM][FF] -> w1t [E][FF][DIM]; tiles: e x (DIM/128=8 r0) x (FF/64=64 c0) = 4096
        int t = q * 4 + r;
        int e = t >> 9, rem = t & 511;
        int r0 = (rem >> 6) << 7, c0 = (rem & 63) << 6;
        transpose_tile128(W1 + (size_t)e * DIM * FF, w1t + (size_t)e * FF * DIM,
                          DIM, FF, r0, c0, smem);
    } else if (r < 6) {
        // convert x: 2048 slots x 2048 elems
        int i = (q * 2 + (r - 4)) * 2048 + tid * 8;
        float4 a = *(const float4*)(x + i);
        float4 b = *(const float4*)(x + i + 4);
        half8 h;
        h[0] = (_Float16)a.x; h[1] = (_Float16)a.y; h[2] = (_Float16)a.z; h[3] = (_Float16)a.w;
        h[4] = (_Float16)b.x; h[5] = (_Float16)b.y; h[6] = (_Float16)b.z; h[7] = (_Float16)b.w;
        *(half8*)(xh + i) = h;
    } else {
        // router: 1024 slots x 4 tokens
        float* wr = (float*)smem;   // 32 KB
        for (int i = tid; i < NE * DIM / 4; i += 256)
            ((float4*)wr)[i] = ((const float4*)Wr)[i];
        __syncthreads();
        int w = tid >> 6, lane = tid & 63;
        int t = q * 4 + w;
        float acc[NE] = {};
        for (int j = 0; j < DIM / 64; ++j) {
            float xv = x[t * DIM + j * 64 + lane];
#pragma unroll
            for (int e = 0; e < NE; ++e)
                acc[e] += xv * wr[e * DIM + j * 64 + lane];
        }
#pragma unroll
        for (int e = 0; e < NE; ++e) {
#pragma unroll
            for (int s = 32; s; s >>= 1) acc[e] += __shfl_xor(acc[e], s, 64);
        }
        if (lane == 0) {
            int b0 = 0; float m0 = acc[0];
#pragma unroll
            for (int e = 1; e < NE; ++e) { if (acc[e] > m0) { m0 = acc[e]; b0 = e; } }
            int b1 = -1; float m1 = -1e30f;
#pragma unroll
            for (int e = 0; e < NE; ++e) { if (e != b0 && acc[e] > m1) { m1 = acc[e]; b1 = e; } }
            float z = __expf(m1 - m0);
            float zz = 1.0f / (1.0f + z);
            int p0 = atomicAdd(&counts[b0], 1);
            int p1 = atomicAdd(&counts[b1], 1);
            tok_e[2 * t] = b0;  tok_e[2 * t + 1] = b1;
            tok_w[2 * t] = zz;  tok_w[2 * t + 1] = z * zz;
            tok_pos[2 * t] = p0; tok_pos[2 * t + 1] = p1;
            __threadfence();   // make this writer's stores agent-visible
        }
        __syncthreads();
        if (tid == 0)
            __hip_atomic_fetch_add(rdone, 1, __ATOMIC_RELEASE, __HIP_MEMORY_SCOPE_AGENT);
    }
}

// standalone 64x64 transpose kernel (fallback tiers: W2)
__global__ __launch_bounds__(256) void k_transpose(const float* __restrict__ src,
                                                   _Float16* __restrict__ dst,
                                                   int R, int C) {
    __shared__ float t[64][65];
    int e = blockIdx.z;
    const float* s = src + (size_t)e * R * C;
    _Float16* d = dst + (size_t)e * C * R;
    int r0 = blockIdx.y * 64, c0 = blockIdx.x * 64;
    int tid = threadIdx.x;
    int rr = tid >> 4, cc = (tid & 15) * 4;
#pragma unroll
    for (int i = 0; i < 4; ++i) {
        float4 v = *(const float4*)(s + (size_t)(r0 + rr + i * 16) * C + c0 + cc);
        t[rr + i * 16][cc] = v.x; t[rr + i * 16][cc + 1] = v.y;
        t[rr + i * 16][cc + 2] = v.z; t[rr + i * 16][cc + 3] = v.w;
    }
    __syncthreads();
    int f = tid >> 3, ch = tid & 7;
#pragma unroll
    for (int j = 0; j < 2; ++j) {
        int fr = f + j * 32;
        half8 v;
#pragma unroll
        for (int u = 0; u < 8; ++u) v[u] = (_Float16)t[ch * 8 + u][fr];
        *(half8*)(d + (size_t)(c0 + fr) * R + r0 + ch * 8) = v;
    }
}

// ---------------- 128x128 grouped GEMM body (proven round-4 structure) ----------------
template<int K, int NOUT, bool GATHER, bool GELU>
__device__ __forceinline__ void ffn128_body(
    const _Float16* __restrict__ Abase,
    const _Float16* __restrict__ Wbase,
    const int* __restrict__ counts,
    const int* __restrict__ offs,
    const int* __restrict__ list_tok,
    _Float16* __restrict__ Out,
    int e, int mt, int f0, _Float16* lds) {

    int base = offs[e] + mt * 128;
    int valid = counts[e] - mt * 128;

    int tid = threadIdx.x;
    int wid = tid >> 6, lane = tid & 63;

    const char* AB = (const char*)Abase;
    const char* WB = (const char*)(Wbase + (size_t)e * NOUT * K);

    size_t aoff[4]; unsigned boff[4];
#pragma unroll
    for (int i = 0; i < 4; ++i) {
        int g = wid * 256 + i * 64 + lane;
        int r = g >> 3;
        int c = (g & 7) ^ (r & 7);
        int rr = (r < valid) ? r : (valid - 1);
        unsigned arow = GATHER ? (unsigned)list_tok[base + rr] : (unsigned)(base + rr);
        aoff[i] = (size_t)arow * (K * 2) + c * 16;
        boff[i] = (unsigned)(f0 + r) * (unsigned)(K * 2) + c * 16;
    }

    floatx4 acc[4][4];
#pragma unroll
    for (int m = 0; m < 4; ++m)
#pragma unroll
        for (int n = 0; n < 4; ++n) acc[m][n] = (floatx4){0.f, 0.f, 0.f, 0.f};

    int la = lane & 15, lb = lane >> 4;
    int wm = (wid >> 1) * 64, wn = (wid & 1) * 64;

#pragma unroll
    for (int i = 0; i < 4; ++i)
        gl_lds16(AB + aoff[i], lds + wid * 2048 + i * 512);
#pragma unroll
    for (int i = 0; i < 4; ++i)
        gl_lds16(WB + boff[i], lds + 16384 + wid * 2048 + i * 512);
    asm volatile("s_waitcnt vmcnt(0)" ::: "memory");
    __builtin_amdgcn_s_barrier();
    __builtin_amdgcn_sched_barrier(0);

    constexpr int NT = K / 64;
#pragma unroll 2
    for (int t = 0; t < NT; ++t) {
        int cur = t & 1;
        if (t + 1 < NT) {
            size_t kadv = (size_t)(t + 1) * 128;
            _Float16* Ad = lds + (cur ^ 1) * 8192;
            _Float16* Bd = lds + 16384 + (cur ^ 1) * 8192;
#pragma unroll
            for (int i = 0; i < 4; ++i)
                gl_lds16(AB + aoff[i] + kadv, Ad + wid * 2048 + i * 512);
#pragma unroll
            for (int i = 0; i < 4; ++i)
                gl_lds16(WB + boff[i] + kadv, Bd + wid * 2048 + i * 512);
        }
        const _Float16* Ac = lds + cur * 8192;
        const _Float16* Bc = lds + 16384 + cur * 8192;
#pragma unroll
        for (int kk = 0; kk < 2; ++kk) {
            half8 af[4], bf[4];
#pragma unroll
            for (int m = 0; m < 4; ++m) {
                int row = wm + m * 16 + la;
                int c = kk * 4 + lb;
                af[m] = *(const half8*)(Ac + row * 64 + ((c ^ (row & 7)) * 8));
            }
#pragma unroll
            for (int n = 0; n < 4; ++n) {
                int row = wn + n * 16 + la;
                int c = kk * 4 + lb;
                bf[n] = *(const half8*)(Bc + row * 64 + ((c ^ (row & 7)) * 8));
            }
#pragma unroll
            for (int m = 0; m < 4; ++m)
#pragma unroll
                for (int n = 0; n < 4; ++n)
                    acc[m][n] = __builtin_amdgcn_mfma_f32_16x16x32_f16(af[m], bf[n], acc[m][n], 0, 0, 0);
        }
        __builtin_amdgcn_sched_barrier(0);
        asm volatile("s_waitcnt vmcnt(0)" ::: "memory");
        __builtin_amdgcn_s_barrier();
        __builtin_amdgcn_sched_barrier(0);
    }

    _Float16* tw = lds + wid * 4096;
#pragma unroll
    for (int m = 0; m < 4; ++m)
#pragma unroll
        for (int n = 0; n < 4; ++n) {
            floatx4 v = acc[m][n];
#pragma unroll
            for (int i = 0; i < 4; ++i) {
                float fv = v[i];
                if (GELU) fv = gelu_exact(fv);
                tw[(m * 16 + lb * 4 + i) * 64 + n * 16 + la] = (_Float16)fv;
            }
        }
    asm volatile("s_waitcnt lgkmcnt(0)" ::: "memory");
    __builtin_amdgcn_sched_barrier(0);
#pragma unroll
    for (int i = 0; i < 8; ++i) {
        int gi = i * 64 + lane;
        int row = gi >> 3, c8 = gi & 7;
        half8 v = *(const half8*)(tw + gi * 8);
        int trow = wm + row;
        if (trow < valid)
            *(half8*)(Out + (size_t)(base + trow) * NOUT + f0 + wn + c8 * 8) = v;
    }
}

// plain 128x128 kernel (fallback tiers)
template<int K, int NOUT, bool GATHER, bool GELU>
__global__ __launch_bounds__(256) void k_ffn(
    const _Float16* __restrict__ Abase,
    const _Float16* __restrict__ Wbase,
    const int* __restrict__ tmap,
    const int* __restrict__ counts,
    const int* __restrict__ offs,
    const int* __restrict__ list_tok,
    _Float16* __restrict__ Out) {
    __shared__ _Float16 lds[32768];
    int nt_m = tmap[0];
    if ((int)blockIdx.x >= nt_m) return;
    int ent = tmap[1 + blockIdx.x];
    ffn128_body<K, NOUT, GATHER, GELU>(Abase, Wbase, counts, offs, list_tok, Out,
                                       ent >> 16, ent & 0xffff, blockIdx.y * 128, lds);
}

// ---------------- FUSED: FFN1 (128x128, gather+GELU) + W2 transpose (128x64 swizzled tiles) ----------------
// 1D grid, period 10: r<2 -> FFN1 slot f=q*2+r; r>=2 -> transpose tile t=q*8+(r-2), 4096 tiles.
__global__ __launch_bounds__(256) void k_ffn1_fused(
    const _Float16* __restrict__ xh,
    const _Float16* __restrict__ w1t,
    const int* __restrict__ tmap,
    const int* __restrict__ counts,
    const int* __restrict__ offs,
    const int* __restrict__ list_tok,
    _Float16* __restrict__ hbuf,
    const float* __restrict__ W2,
    _Float16* __restrict__ w2t) {
    __shared__ _Float16 lds[32768];   // 64 KB; transpose path reuses 32 KB as fp32
    int bid = blockIdx.x;
    int q = bid / 10, r = bid % 10;
    if (r < 2) {
        int f = q * 2 + r;
        int nt_m = tmap[0];
        int tile = f >> 5;
        if (tile >= nt_m) return;
        int ent = tmap[1 + tile];
        ffn128_body<DIM, FF, true, true>(xh, w1t, counts, offs, list_tok, hbuf,
                                         ent >> 16, ent & 0xffff, (f & 31) * 128, lds);
    } else {
        // W2 [E][FF][DIM] -> w2t [E][DIM][FF]: R=FF, C=DIM; tiles e x (FF/128=32) x (DIM/64=16)
        int t = q * 8 + (r - 2);
        if (t >= 8 * 32 * 16) return;
        int e = t >> 9, rem = t & 511;
        int r0 = (rem >> 4) << 7, c0 = (rem & 15) << 6;
        transpose_tile128(W2 + (size_t)e * FF * DIM, w2t + (size_t)e * DIM * FF,
                          FF, DIM, r0, c0, (char*)lds);
    }
}

// ---------------- 256x256 grouped GEMM (FFN2 split-K), round-5 structure ----------------
template<int K, int NOUT, int KSPAN, bool GATHER, bool GELU>
__global__ __launch_bounds__(512, 2) void k_ffn256(
    const _Float16* __restrict__ Abase,
    const _Float16* __restrict__ Wbase,
    const int* __restrict__ tmap,
    const int* __restrict__ counts,
    const int* __restrict__ offs,
    const int* __restrict__ list_tok,
    _Float16* __restrict__ Out) {

    int nt_m = tmap[0];
    if ((int)blockIdx.x >= nt_m) return;
    int ent = tmap[1 + blockIdx.x];
    int e = ent >> 16, mt = ent & 0xffff;
    int base = offs[e] + mt * 256;
    int valid = counts[e] - mt * 256;
    int f0 = blockIdx.y * 256;
    int kbase = blockIdx.z * KSPAN;
    Out += (size_t)blockIdx.z * ((size_t)NSLOT * NOUT);

    __shared__ _Float16 lds[65536];

    int tid = threadIdx.x;
    int wid = tid >> 6, lane = tid & 63;

    const char* AB = (const char*)Abase;
    const char* WB = (const char*)(Wbase + (size_t)e * NOUT * K);

    size_t aoff[4]; unsigned boff[4];
#pragma unroll
    for (int i = 0; i < 4; ++i) {
        int g = i * 512 + tid;
        int r = g >> 3;
        int c = (g & 7) ^ (r & 7);
        int rr = (r < valid) ? r : (valid - 1);
        unsigned arow = GATHER ? (unsigned)list_tok[base + rr] : (unsigned)(base + rr);
        aoff[i] = (size_t)arow * (K * 2) + c * 16 + (size_t)kbase * 2;
        boff[i] = (unsigned)(f0 + r) * (unsigned)(K * 2) + c * 16 + (unsigned)kbase * 2;
    }

    floatx4 acc[8][4];
#pragma unroll
    for (int m = 0; m < 8; ++m)
#pragma unroll
        for (int n = 0; n < 4; ++n) acc[m][n] = (floatx4){0.f, 0.f, 0.f, 0.f};

    int la = lane & 15, lb = lane >> 4;
    int wmb = (wid >> 2) * 128, wnb = (wid & 3) * 64;

#pragma unroll
    for (int i = 0; i < 4; ++i)
        gl_lds16(AB + aoff[i], lds + i * 4096 + wid * 512);
#pragma unroll
    for (int i = 0; i < 4; ++i)
        gl_lds16(WB + boff[i], lds + 32768 + i * 4096 + wid * 512);
    asm volatile("s_waitcnt vmcnt(0)" ::: "memory");
    __builtin_amdgcn_s_barrier();
    __builtin_amdgcn_sched_barrier(0);

    constexpr int NT = KSPAN / 64;
#pragma unroll 2
    for (int t = 0; t < NT; ++t) {
        int cur = t & 1;
        if (t + 1 < NT) {
            size_t adv = (size_t)(t + 1) * 128;
            _Float16* Ad = lds + (cur ^ 1) * 16384;
            _Float16* Bd = lds + 32768 + (cur ^ 1) * 16384;
#pragma unroll
            for (int i = 0; i < 4; ++i)
                gl_lds16(AB + aoff[i] + adv, Ad + i * 4096 + wid * 512);
#pragma unroll
            for (int i = 0; i < 4; ++i)
                gl_lds16(WB + boff[i] + adv, Bd + i * 4096 + wid * 512);
        }
        const _Float16* Ac = lds + cur * 16384;
        const _Float16* Bc = lds + 32768 + cur * 16384;
#pragma unroll
        for (int kk = 0; kk < 2; ++kk) {
            half8 af[8], bf[4];
#pragma unroll
            for (int n = 0; n < 4; ++n) {
                int row = wnb + n * 16 + la;
                int c = kk * 4 + lb;
                bf[n] = *(const half8*)(Bc + row * 64 + ((c ^ (row & 7)) * 8));
            }
#pragma unroll
            for (int m = 0; m < 8; ++m) {
                int row = wmb + m * 16 + la;
                int c = kk * 4 + lb;
                af[m] = *(const half8*)(Ac + row * 64 + ((c ^ (row & 7)) * 8));
            }
#pragma unroll
            for (int m = 0; m < 8; ++m)
#pragma unroll
                for (int n = 0; n < 4; ++n)
                    acc[m][n] = __builtin_amdgcn_mfma_f32_16x16x32_f16(af[m], bf[n], acc[m][n], 0, 0, 0);
        }
        __builtin_amdgcn_sched_barrier(0);
        asm volatile("s_waitcnt vmcnt(0)" ::: "memory");
        __builtin_amdgcn_s_barrier();
        __builtin_amdgcn_sched_barrier(0);
    }

    _Float16* tw = lds + wid * 4096;
#pragma unroll
    for (int ps = 0; ps < 2; ++ps) {
#pragma unroll
        for (int fi = 0; fi < 4; ++fi)
#pragma unroll
            for (int nf = 0; nf < 4; ++nf) {
                floatx4 v = acc[ps * 4 + fi][nf];
#pragma unroll
                for (int i2 = 0; i2 < 4; ++i2) {
                    float fv = v[i2];
                    if (GELU) fv = gelu_exact(fv);
                    tw[(fi * 16 + lb * 4 + i2) * 64 + nf * 16 + la] = (_Float16)fv;
                }
            }
        asm volatile("s_waitcnt lgkmcnt(0)" ::: "memory");
        __builtin_amdgcn_sched_barrier(0);
#pragma unroll
        for (int i2 = 0; i2 < 8; ++i2) {
            int gi = i2 * 64 + lane;
            int row = gi >> 3, c8 = gi & 7;
            half8 v = *(const half8*)(tw + gi * 8);
            int trow = wmb + ps * 64 + row;
            if (trow < valid)
                *(half8*)(Out + (size_t)(base + trow) * NOUT + f0 + wnb + c8 * 8) = v;
        }
    }
}

// ---------------- combine: out[t] = w0*sum_z y0[z] + w1*sum_z y1[z] ----------------
__global__ __launch_bounds__(256) void k_combine(const _Float16* __restrict__ yp,
                                                 const int* __restrict__ tok_slot,
                                                 const float* __restrict__ tok_w,
                                                 float* __restrict__ out,
                                                 int nsplit) {
    int t = blockIdx.x;
    int d = threadIdx.x * 4;
    int s0 = tok_slot[2 * t], s1 = tok_slot[2 * t + 1];
    float w0 = tok_w[2 * t], w1 = tok_w[2 * t + 1];
    float4 sum0 = {0.f, 0.f, 0.f, 0.f}, sum1 = {0.f, 0.f, 0.f, 0.f};
    for (int z = 0; z < nsplit; ++z) {
        const _Float16* p = yp + (size_t)z * NSLOT * DIM;
        half4 y0 = *(const half4*)(p + (size_t)s0 * DIM + d);
        half4 y1 = *(const half4*)(p + (size_t)s1 * DIM + d);
        sum0.x += (float)y0[0]; sum0.y += (float)y0[1];
        sum0.z += (float)y0[2]; sum0.w += (float)y0[3];
        sum1.x += (float)y1[0]; sum1.y += (float)y1[1];
        sum1.z += (float)y1[2]; sum1.w += (float)y1[3];
    }
    float4 o;
    o.x = w0 * sum0.x + w1 * sum1.x;
    o.y = w0 * sum0.y + w1 * sum1.y;
    o.z = w0 * sum0.z + w1 * sum1.z;
    o.w = w0 * sum0.w + w1 * sum1.w;
    *(float4*)(out + (size_t)t * DIM + d) = o;
}

extern "C" void kernel_launch(void* const* d_in, const int* in_sizes, int n_in,
                              void* d_out, int out_size, void* d_ws, size_t ws_size,
                              hipStream_t stream) {
    const float* x  = (const float*)d_in[0];   // [4096,1024]
    const float* Wr = (const float*)d_in[1];   // [8,1024]
    const float* W1 = (const float*)d_in[2];   // [8,1024,4096]
    const float* W2 = (const float*)d_in[3];   // [8,4096,1024]
    float* out = (float*)d_out;

    char* ws = (char*)d_ws;
    _Float16* w1t  = (_Float16*)ws;                        // [0, 67108864)
    _Float16* xh   = (_Float16*)(ws + 67108864);           // [67108864, 75497472)
    _Float16* hbuf = (_Float16*)(ws + 75497472);           // [75497472, 142606336)
    char* p = ws + 142606336;                              // small arrays (<192 KB)
    int*   counts   = (int*)p;        p += 1024;           // [0..7]=counts, [8]=rdone
    int*   offs     = (int*)p;        p += 1024;
    int*   tmap256  = (int*)p;        p += 1024;
    int*   tmap128  = (int*)p;        p += 1024;
    int*   tok_e    = (int*)p;        p += NSLOT * 4;
    float* tok_w    = (float*)p;      p += NSLOT * 4;
    int*   tok_pos  = (int*)p;        p += NSLOT * 4;
    int*   tok_slot = (int*)p;        p += NSLOT * 4;
    int*   list_tok = (int*)p;        p += NSLOT * 4;
    const size_t OFF_EXT = 142606336 + 196608;             // 142,802,944
    const size_t SZ_Y  = (size_t)NSLOT * DIM * 2;          // 16,777,216 per split
    const size_t SZ_WT = (size_t)NE * DIM * FF * 2;        // 67,108,864

    // tier select (deterministic, by ws_size only)
    bool fused = (ws_size >= OFF_EXT + SZ_WT);             // 209,911,808: separate w2t

    hipMemsetAsync(counts, 0, 64, stream);                 // counts + rdone
    // fused W1T + convert_x + router + prefix/slots: 7*1024 + 1 blocks
    k_prep<<<7 * 1024 + 1, 256, 0, stream>>>(x, Wr, W1, w1t, xh,
                                             counts, offs, tmap256, tmap128,
                                             tok_e, tok_w, tok_pos, tok_slot, list_tok);

    if (fused) {
        _Float16* w2t = (_Float16*)(ws + OFF_EXT);         // separate: concurrent with w1t
        _Float16* yp  = (_Float16*)ws;                     // overlays dead w1t (4*16.7MB <= 64MB)
        // FFN1 (128x128) + W2 transpose (128x64 swizzled tiles), interleaved blocks
        k_ffn1_fused<<<10 * 1152, 256, 0, stream>>>(
            xh, w1t, tmap128, counts, offs, list_tok, hbuf, W2, w2t);
        // FFN2: 256x256 split-K=4 partials into yp
        k_ffn256<FF, DIM, 1024, false, false>
            <<<dim3(NSLOT / 256 + NE, DIM / 256, 4), 512, 0, stream>>>(
                hbuf, w2t, tmap256, counts, offs, list_tok, yp);
        k_combine<<<NTOK, 256, 0, stream>>>(yp, tok_slot, tok_w, out, 4);
    } else {
        _Float16* w2t = w1t;                               // alias (sequential use)
        _Float16* yp  = (_Float16*)(ws + OFF_EXT);
        int nsplit = (ws_size >= OFF_EXT + 2 * SZ_Y) ? 2 : 1;
        k_ffn<DIM, FF, true, true>
            <<<dim3(NSLOT / 128 + NE, FF / 128), 256, 0, stream>>>(
                xh, w1t, tmap128, counts, offs, list_tok, hbuf);
        k_transpose<<<dim3(DIM / 64, FF / 64, NE), 256, 0, stream>>>(W2, w2t, FF, DIM);
        if (nsplit == 2) {
            k_ffn256<FF, DIM, 2048, false, false>
                <<<dim3(NSLOT / 256 + NE, DIM / 256, 2), 512, 0, stream>>>(
                    hbuf, w2t, tmap256, counts, offs, list_tok, yp);
        } else {
            k_ffn<FF, DIM, false, false>
                <<<dim3(NSLOT / 128 + NE, DIM / 128), 256, 0, stream>>>(
                    hbuf, w2t, tmap128, counts, offs, list_tok, yp);
        }
        k_combine<<<NTOK, 256, 0, stream>>>(yp, tok_slot, tok_w, out, nsplit);
    }
}

// Round 9
// 368.932 us; speedup vs baseline: 1.4362x; 1.4362x over previous
//
#include <hip/hip_runtime.h>
#include <hip/hip_bf16.h>
#include <hip/hip_fp16.h>

// Problem constants (B=2, T=2048, DIM=1024, FF=4096, E=8, TOPK=2)
#define NTOK 4096
#define DIM 1024
#define FF 4096
#define NE 8
#define NSLOT 8192   // NTOK * TOPK

typedef _Float16 half8 __attribute__((ext_vector_type(8)));
typedef _Float16 half4 __attribute__((ext_vector_type(4)));
typedef float floatx4 __attribute__((ext_vector_type(4)));

__device__ __forceinline__ float gelu_exact(float x) {
    return 0.5f * x * (1.0f + erff(x * 0.70710678118654752f));
}

__device__ __forceinline__ void gl_lds16(const void* g, void* l) {
    __builtin_amdgcn_global_load_lds(
        (const __attribute__((address_space(1))) void*)g,
        (__attribute__((address_space(3))) void*)l, 16, 0, 0);
}

// ---------------- 128r x 64c transpose tile: src fp32 [R][C] -> dst fp16 [C][R] ----------------
// LDS float [128][64], XOR-swizzled col: c_phys = c ^ (((r>>3)&15)<<2).
// Store: 2-way (free). Read: 32 distinct banks, 2 lanes each (free).
__device__ __forceinline__ void transpose_tile128(const float* __restrict__ s,
                                                  _Float16* __restrict__ d,
                                                  int R, int C, int r0, int c0,
                                                  char* smem) {
    float* t = (float*)smem;   // [128][64] swizzled
    int tid = threadIdx.x;
    int rr = tid >> 4, cc = (tid & 15) * 4;
#pragma unroll
    for (int i = 0; i < 8; ++i) {
        int r = rr + i * 16;
        float4 v = *(const float4*)(s + (size_t)(r0 + r) * C + c0 + cc);
        *(float4*)(t + r * 64 + (cc ^ (((r >> 3) & 15) << 2))) = v;
    }
    __syncthreads();
#pragma unroll
    for (int j = 0; j < 4; ++j) {
        int chunk = j * 256 + tid;
        int fr = chunk >> 4, ch = chunk & 15;
        half8 v;
#pragma unroll
        for (int u = 0; u < 8; ++u)
            v[u] = (_Float16)t[(ch * 8 + u) * 64 + (fr ^ (ch << 2))];
        *(half8*)(d + (size_t)(c0 + fr) * R + r0 + ch * 8) = v;
    }
}

// ---------------- k_prep: fused W1-transpose + convert_x + router (NO cross-block sync) ----------------
// 1D grid 7*1024: q=bid/7, r=bid%7: r<4 -> W1T tile; r in {4,5} -> convert_x; r=6 -> router.
__global__ __launch_bounds__(256) void k_prep(
    const float* __restrict__ x,
    const float* __restrict__ Wr,
    const float* __restrict__ W1,
    _Float16* __restrict__ w1t,
    _Float16* __restrict__ xh,
    int* __restrict__ counts,
    int* __restrict__ tok_e,
    float* __restrict__ tok_w,
    int* __restrict__ tok_pos) {
    __shared__ char smem[32768];
    int bid = blockIdx.x;
    int tid = threadIdx.x;
    int q = bid / 7, r = bid % 7;
    if (r < 4) {
        // W1 [E][DIM][FF] -> w1t [E][FF][DIM]; tiles: e x (DIM/128=8) x (FF/64=64) = 4096
        int t = q * 4 + r;
        int e = t >> 9, rem = t & 511;
        int r0 = (rem >> 6) << 7, c0 = (rem & 63) << 6;
        transpose_tile128(W1 + (size_t)e * DIM * FF, w1t + (size_t)e * FF * DIM,
                          DIM, FF, r0, c0, smem);
    } else if (r < 6) {
        // convert x: 2048 slots x 2048 elems
        int i = (q * 2 + (r - 4)) * 2048 + tid * 8;
        float4 a = *(const float4*)(x + i);
        float4 b = *(const float4*)(x + i + 4);
        half8 h;
        h[0] = (_Float16)a.x; h[1] = (_Float16)a.y; h[2] = (_Float16)a.z; h[3] = (_Float16)a.w;
        h[4] = (_Float16)b.x; h[5] = (_Float16)b.y; h[6] = (_Float16)b.z; h[7] = (_Float16)b.w;
        *(half8*)(xh + i) = h;
    } else {
        // router: 1024 slots x 4 tokens
        float* wr = (float*)smem;   // 32 KB
        for (int i = tid; i < NE * DIM / 4; i += 256)
            ((float4*)wr)[i] = ((const float4*)Wr)[i];
        __syncthreads();
        int w = tid >> 6, lane = tid & 63;
        int t = q * 4 + w;
        float acc[NE] = {};
        for (int j = 0; j < DIM / 64; ++j) {
            float xv = x[t * DIM + j * 64 + lane];
#pragma unroll
            for (int e = 0; e < NE; ++e)
                acc[e] += xv * wr[e * DIM + j * 64 + lane];
        }
#pragma unroll
        for (int e = 0; e < NE; ++e) {
#pragma unroll
            for (int s = 32; s; s >>= 1) acc[e] += __shfl_xor(acc[e], s, 64);
        }
        if (lane == 0) {
            int b0 = 0; float m0 = acc[0];
#pragma unroll
            for (int e = 1; e < NE; ++e) { if (acc[e] > m0) { m0 = acc[e]; b0 = e; } }
            int b1 = -1; float m1 = -1e30f;
#pragma unroll
            for (int e = 0; e < NE; ++e) { if (e != b0 && acc[e] > m1) { m1 = acc[e]; b1 = e; } }
            float z = __expf(m1 - m0);
            float zz = 1.0f / (1.0f + z);
            int p0 = atomicAdd(&counts[b0], 1);
            int p1 = atomicAdd(&counts[b1], 1);
            tok_e[2 * t] = b0;  tok_e[2 * t + 1] = b1;
            tok_w[2 * t] = zz;  tok_w[2 * t + 1] = z * zz;
            tok_pos[2 * t] = p0; tok_pos[2 * t + 1] = p1;
        }
    }
}

// standalone 64x64 transpose kernel (fallback tiers: W2)
__global__ __launch_bounds__(256) void k_transpose(const float* __restrict__ src,
                                                   _Float16* __restrict__ dst,
                                                   int R, int C) {
    __shared__ float t[64][65];
    int e = blockIdx.z;
    const float* s = src + (size_t)e * R * C;
    _Float16* d = dst + (size_t)e * C * R;
    int r0 = blockIdx.y * 64, c0 = blockIdx.x * 64;
    int tid = threadIdx.x;
    int rr = tid >> 4, cc = (tid & 15) * 4;
#pragma unroll
    for (int i = 0; i < 4; ++i) {
        float4 v = *(const float4*)(s + (size_t)(r0 + rr + i * 16) * C + c0 + cc);
        t[rr + i * 16][cc] = v.x; t[rr + i * 16][cc + 1] = v.y;
        t[rr + i * 16][cc + 2] = v.z; t[rr + i * 16][cc + 3] = v.w;
    }
    __syncthreads();
    int f = tid >> 3, ch = tid & 7;
#pragma unroll
    for (int j = 0; j < 2; ++j) {
        int fr = f + j * 32;
        half8 v;
#pragma unroll
        for (int u = 0; u < 8; ++u) v[u] = (_Float16)t[ch * 8 + u][fr];
        *(half8*)(d + (size_t)(c0 + fr) * R + r0 + ch * 8) = v;
    }
}

// ---------------- prefix + tmaps + slots (single block, separate kernel = cheap fence) ----------------
__global__ __launch_bounds__(256) void k_prefix_slots(
    const int* __restrict__ counts, int* __restrict__ offs,
    int* __restrict__ tmap256, int* __restrict__ tmap128,
    const int* __restrict__ tok_e, const int* __restrict__ tok_pos,
    int* __restrict__ tok_slot, int* __restrict__ list_tok) {
    __shared__ int soffs[NE];
    if (threadIdx.x == 0) {
        int s = 0, n2 = 0, n1 = 0;
        for (int e = 0; e < NE; ++e) {
            offs[e] = s; soffs[e] = s;
            int c = counts[e];
            for (int mt = 0; mt * 256 < c; ++mt) tmap256[1 + n2++] = (e << 16) | mt;
            for (int mt = 0; mt * 128 < c; ++mt) tmap128[1 + n1++] = (e << 16) | mt;
            s += c;
        }
        offs[NE] = s;
        tmap256[0] = n2;
        tmap128[0] = n1;
    }
    __syncthreads();
    for (int idx = threadIdx.x; idx < NSLOT; idx += 256) {
        int e = tok_e[idx];
        int slot = soffs[e] + tok_pos[idx];
        tok_slot[idx] = slot;
        list_tok[slot] = idx >> 1;
    }
}

// ---------------- 128x128 grouped GEMM body (proven round-4 structure) ----------------
template<int K, int NOUT, bool GATHER, bool GELU>
__device__ __forceinline__ void ffn128_body(
    const _Float16* __restrict__ Abase,
    const _Float16* __restrict__ Wbase,
    const int* __restrict__ counts,
    const int* __restrict__ offs,
    const int* __restrict__ list_tok,
    _Float16* __restrict__ Out,
    int e, int mt, int f0, _Float16* lds) {

    int base = offs[e] + mt * 128;
    int valid = counts[e] - mt * 128;

    int tid = threadIdx.x;
    int wid = tid >> 6, lane = tid & 63;

    const char* AB = (const char*)Abase;
    const char* WB = (const char*)(Wbase + (size_t)e * NOUT * K);

    size_t aoff[4]; unsigned boff[4];
#pragma unroll
    for (int i = 0; i < 4; ++i) {
        int g = wid * 256 + i * 64 + lane;
        int r = g >> 3;
        int c = (g & 7) ^ (r & 7);
        int rr = (r < valid) ? r : (valid - 1);
        unsigned arow = GATHER ? (unsigned)list_tok[base + rr] : (unsigned)(base + rr);
        aoff[i] = (size_t)arow * (K * 2) + c * 16;
        boff[i] = (unsigned)(f0 + r) * (unsigned)(K * 2) + c * 16;
    }

    floatx4 acc[4][4];
#pragma unroll
    for (int m = 0; m < 4; ++m)
#pragma unroll
        for (int n = 0; n < 4; ++n) acc[m][n] = (floatx4){0.f, 0.f, 0.f, 0.f};

    int la = lane & 15, lb = lane >> 4;
    int wm = (wid >> 1) * 64, wn = (wid & 1) * 64;

#pragma unroll
    for (int i = 0; i < 4; ++i)
        gl_lds16(AB + aoff[i], lds + wid * 2048 + i * 512);
#pragma unroll
    for (int i = 0; i < 4; ++i)
        gl_lds16(WB + boff[i], lds + 16384 + wid * 2048 + i * 512);
    asm volatile("s_waitcnt vmcnt(0)" ::: "memory");
    __builtin_amdgcn_s_barrier();
    __builtin_amdgcn_sched_barrier(0);

    constexpr int NT = K / 64;
#pragma unroll 2
    for (int t = 0; t < NT; ++t) {
        int cur = t & 1;
        if (t + 1 < NT) {
            size_t kadv = (size_t)(t + 1) * 128;
            _Float16* Ad = lds + (cur ^ 1) * 8192;
            _Float16* Bd = lds + 16384 + (cur ^ 1) * 8192;
#pragma unroll
            for (int i = 0; i < 4; ++i)
                gl_lds16(AB + aoff[i] + kadv, Ad + wid * 2048 + i * 512);
#pragma unroll
            for (int i = 0; i < 4; ++i)
                gl_lds16(WB + boff[i] + kadv, Bd + wid * 2048 + i * 512);
        }
        const _Float16* Ac = lds + cur * 8192;
        const _Float16* Bc = lds + 16384 + cur * 8192;
#pragma unroll
        for (int kk = 0; kk < 2; ++kk) {
            half8 af[4], bf[4];
#pragma unroll
            for (int m = 0; m < 4; ++m) {
                int row = wm + m * 16 + la;
                int c = kk * 4 + lb;
                af[m] = *(const half8*)(Ac + row * 64 + ((c ^ (row & 7)) * 8));
            }
#pragma unroll
            for (int n = 0; n < 4; ++n) {
                int row = wn + n * 16 + la;
                int c = kk * 4 + lb;
                bf[n] = *(const half8*)(Bc + row * 64 + ((c ^ (row & 7)) * 8));
            }
#pragma unroll
            for (int m = 0; m < 4; ++m)
#pragma unroll
                for (int n = 0; n < 4; ++n)
                    acc[m][n] = __builtin_amdgcn_mfma_f32_16x16x32_f16(af[m], bf[n], acc[m][n], 0, 0, 0);
        }
        __builtin_amdgcn_sched_barrier(0);
        asm volatile("s_waitcnt vmcnt(0)" ::: "memory");
        __builtin_amdgcn_s_barrier();
        __builtin_amdgcn_sched_barrier(0);
    }

    _Float16* tw = lds + wid * 4096;
#pragma unroll
    for (int m = 0; m < 4; ++m)
#pragma unroll
        for (int n = 0; n < 4; ++n) {
            floatx4 v = acc[m][n];
#pragma unroll
            for (int i = 0; i < 4; ++i) {
                float fv = v[i];
                if (GELU) fv = gelu_exact(fv);
                tw[(m * 16 + lb * 4 + i) * 64 + n * 16 + la] = (_Float16)fv;
            }
        }
    asm volatile("s_waitcnt lgkmcnt(0)" ::: "memory");
    __builtin_amdgcn_sched_barrier(0);
#pragma unroll
    for (int i = 0; i < 8; ++i) {
        int gi = i * 64 + lane;
        int row = gi >> 3, c8 = gi & 7;
        half8 v = *(const half8*)(tw + gi * 8);
        int trow = wm + row;
        if (trow < valid)
            *(half8*)(Out + (size_t)(base + trow) * NOUT + f0 + wn + c8 * 8) = v;
    }
}

// plain 128x128 kernel (fallback tiers)
template<int K, int NOUT, bool GATHER, bool GELU>
__global__ __launch_bounds__(256) void k_ffn(
    const _Float16* __restrict__ Abase,
    const _Float16* __restrict__ Wbase,
    const int* __restrict__ tmap,
    const int* __restrict__ counts,
    const int* __restrict__ offs,
    const int* __restrict__ list_tok,
    _Float16* __restrict__ Out) {
    __shared__ _Float16 lds[32768];
    int nt_m = tmap[0];
    if ((int)blockIdx.x >= nt_m) return;
    int ent = tmap[1 + blockIdx.x];
    ffn128_body<K, NOUT, GATHER, GELU>(Abase, Wbase, counts, offs, list_tok, Out,
                                       ent >> 16, ent & 0xffff, blockIdx.y * 128, lds);
}

// ---------------- FUSED: FFN1 (128x128, gather+GELU) + W2 transpose (128x64 swizzled tiles) ----------------
// 1D grid, period 10: r<2 -> FFN1 slot f=q*2+r; r>=2 -> transpose tile t=q*8+(r-2), 4096 tiles.
__global__ __launch_bounds__(256) void k_ffn1_fused(
    const _Float16* __restrict__ xh,
    const _Float16* __restrict__ w1t,
    const int* __restrict__ tmap,
    const int* __restrict__ counts,
    const int* __restrict__ offs,
    const int* __restrict__ list_tok,
    _Float16* __restrict__ hbuf,
    const float* __restrict__ W2,
    _Float16* __restrict__ w2t) {
    __shared__ _Float16 lds[32768];   // 64 KB; transpose path reuses 32 KB as fp32
    int bid = blockIdx.x;
    int q = bid / 10, r = bid % 10;
    if (r < 2) {
        int f = q * 2 + r;
        int nt_m = tmap[0];
        int tile = f >> 5;
        if (tile >= nt_m) return;
        int ent = tmap[1 + tile];
        ffn128_body<DIM, FF, true, true>(xh, w1t, counts, offs, list_tok, hbuf,
                                         ent >> 16, ent & 0xffff, (f & 31) * 128, lds);
    } else {
        // W2 [E][FF][DIM] -> w2t [E][DIM][FF]: R=FF, C=DIM; tiles e x (FF/128=32) x (DIM/64=16)
        int t = q * 8 + (r - 2);
        if (t >= 8 * 32 * 16) return;
        int e = t >> 9, rem = t & 511;
        int r0 = (rem >> 4) << 7, c0 = (rem & 15) << 6;
        transpose_tile128(W2 + (size_t)e * FF * DIM, w2t + (size_t)e * DIM * FF,
                          FF, DIM, r0, c0, (char*)lds);
    }
}

// ---------------- 256x256 grouped GEMM (FFN2 split-K), round-5 structure ----------------
template<int K, int NOUT, int KSPAN, bool GATHER, bool GELU>
__global__ __launch_bounds__(512, 2) void k_ffn256(
    const _Float16* __restrict__ Abase,
    const _Float16* __restrict__ Wbase,
    const int* __restrict__ tmap,
    const int* __restrict__ counts,
    const int* __restrict__ offs,
    const int* __restrict__ list_tok,
    _Float16* __restrict__ Out) {

    int nt_m = tmap[0];
    if ((int)blockIdx.x >= nt_m) return;
    int ent = tmap[1 + blockIdx.x];
    int e = ent >> 16, mt = ent & 0xffff;
    int base = offs[e] + mt * 256;
    int valid = counts[e] - mt * 256;
    int f0 = blockIdx.y * 256;
    int kbase = blockIdx.z * KSPAN;
    Out += (size_t)blockIdx.z * ((size_t)NSLOT * NOUT);

    __shared__ _Float16 lds[65536];

    int tid = threadIdx.x;
    int wid = tid >> 6, lane = tid & 63;

    const char* AB = (const char*)Abase;
    const char* WB = (const char*)(Wbase + (size_t)e * NOUT * K);

    size_t aoff[4]; unsigned boff[4];
#pragma unroll
    for (int i = 0; i < 4; ++i) {
        int g = i * 512 + tid;
        int r = g >> 3;
        int c = (g & 7) ^ (r & 7);
        int rr = (r < valid) ? r : (valid - 1);
        unsigned arow = GATHER ? (unsigned)list_tok[base + rr] : (unsigned)(base + rr);
        aoff[i] = (size_t)arow * (K * 2) + c * 16 + (size_t)kbase * 2;
        boff[i] = (unsigned)(f0 + r) * (unsigned)(K * 2) + c * 16 + (unsigned)kbase * 2;
    }

    floatx4 acc[8][4];
#pragma unroll
    for (int m = 0; m < 8; ++m)
#pragma unroll
        for (int n = 0; n < 4; ++n) acc[m][n] = (floatx4){0.f, 0.f, 0.f, 0.f};

    int la = lane & 15, lb = lane >> 4;
    int wmb = (wid >> 2) * 128, wnb = (wid & 3) * 64;

#pragma unroll
    for (int i = 0; i < 4; ++i)
        gl_lds16(AB + aoff[i], lds + i * 4096 + wid * 512);
#pragma unroll
    for (int i = 0; i < 4; ++i)
        gl_lds16(WB + boff[i], lds + 32768 + i * 4096 + wid * 512);
    asm volatile("s_waitcnt vmcnt(0)" ::: "memory");
    __builtin_amdgcn_s_barrier();
    __builtin_amdgcn_sched_barrier(0);

    constexpr int NT = KSPAN / 64;
#pragma unroll 2
    for (int t = 0; t < NT; ++t) {
        int cur = t & 1;
        if (t + 1 < NT) {
            size_t adv = (size_t)(t + 1) * 128;
            _Float16* Ad = lds + (cur ^ 1) * 16384;
            _Float16* Bd = lds + 32768 + (cur ^ 1) * 16384;
#pragma unroll
            for (int i = 0; i < 4; ++i)
                gl_lds16(AB + aoff[i] + adv, Ad + i * 4096 + wid * 512);
#pragma unroll
            for (int i = 0; i < 4; ++i)
                gl_lds16(WB + boff[i] + adv, Bd + i * 4096 + wid * 512);
        }
        const _Float16* Ac = lds + cur * 16384;
        const _Float16* Bc = lds + 32768 + cur * 16384;
#pragma unroll
        for (int kk = 0; kk < 2; ++kk) {
            half8 af[8], bf[4];
#pragma unroll
            for (int n = 0; n < 4; ++n) {
                int row = wnb + n * 16 + la;
                int c = kk * 4 + lb;
                bf[n] = *(const half8*)(Bc + row * 64 + ((c ^ (row & 7)) * 8));
            }
#pragma unroll
            for (int m = 0; m < 8; ++m) {
                int row = wmb + m * 16 + la;
                int c = kk * 4 + lb;
                af[m] = *(const half8*)(Ac + row * 64 + ((c ^ (row & 7)) * 8));
            }
#pragma unroll
            for (int m = 0; m < 8; ++m)
#pragma unroll
                for (int n = 0; n < 4; ++n)
                    acc[m][n] = __builtin_amdgcn_mfma_f32_16x16x32_f16(af[m], bf[n], acc[m][n], 0, 0, 0);
        }
        __builtin_amdgcn_sched_barrier(0);
        asm volatile("s_waitcnt vmcnt(0)" ::: "memory");
        __builtin_amdgcn_s_barrier();
        __builtin_amdgcn_sched_barrier(0);
    }

    _Float16* tw = lds + wid * 4096;
#pragma unroll
    for (int ps = 0; ps < 2; ++ps) {
#pragma unroll
        for (int fi = 0; fi < 4; ++fi)
#pragma unroll
            for (int nf = 0; nf < 4; ++nf) {
                floatx4 v = acc[ps * 4 + fi][nf];
#pragma unroll
                for (int i2 = 0; i2 < 4; ++i2) {
                    float fv = v[i2];
                    if (GELU) fv = gelu_exact(fv);
                    tw[(fi * 16 + lb * 4 + i2) * 64 + nf * 16 + la] = (_Float16)fv;
                }
            }
        asm volatile("s_waitcnt lgkmcnt(0)" ::: "memory");
        __builtin_amdgcn_sched_barrier(0);
#pragma unroll
        for (int i2 = 0; i2 < 8; ++i2) {
            int gi = i2 * 64 + lane;
            int row = gi >> 3, c8 = gi & 7;
            half8 v = *(const half8*)(tw + gi * 8);
            int trow = wmb + ps * 64 + row;
            if (trow < valid)
                *(half8*)(Out + (size_t)(base + trow) * NOUT + f0 + wnb + c8 * 8) = v;
        }
    }
}

// ---------------- combine: out[t] = w0*sum_z y0[z] + w1*sum_z y1[z] ----------------
__global__ __launch_bounds__(256) void k_combine(const _Float16* __restrict__ yp,
                                                 const int* __restrict__ tok_slot,
                                                 const float* __restrict__ tok_w,
                                                 float* __restrict__ out,
                                                 int nsplit) {
    int t = blockIdx.x;
    int d = threadIdx.x * 4;
    int s0 = tok_slot[2 * t], s1 = tok_slot[2 * t + 1];
    float w0 = tok_w[2 * t], w1 = tok_w[2 * t + 1];
    float4 sum0 = {0.f, 0.f, 0.f, 0.f}, sum1 = {0.f, 0.f, 0.f, 0.f};
    for (int z = 0; z < nsplit; ++z) {
        const _Float16* p = yp + (size_t)z * NSLOT * DIM;
        half4 y0 = *(const half4*)(p + (size_t)s0 * DIM + d);
        half4 y1 = *(const half4*)(p + (size_t)s1 * DIM + d);
        sum0.x += (float)y0[0]; sum0.y += (float)y0[1];
        sum0.z += (float)y0[2]; sum0.w += (float)y0[3];
        sum1.x += (float)y1[0]; sum1.y += (float)y1[1];
        sum1.z += (float)y1[2]; sum1.w += (float)y1[3];
    }
    float4 o;
    o.x = w0 * sum0.x + w1 * sum1.x;
    o.y = w0 * sum0.y + w1 * sum1.y;
    o.z = w0 * sum0.z + w1 * sum1.z;
    o.w = w0 * sum0.w + w1 * sum1.w;
    *(float4*)(out + (size_t)t * DIM + d) = o;
}

extern "C" void kernel_launch(void* const* d_in, const int* in_sizes, int n_in,
                              void* d_out, int out_size, void* d_ws, size_t ws_size,
                              hipStream_t stream) {
    const float* x  = (const float*)d_in[0];   // [4096,1024]
    const float* Wr = (const float*)d_in[1];   // [8,1024]
    const float* W1 = (const float*)d_in[2];   // [8,1024,4096]
    const float* W2 = (const float*)d_in[3];   // [8,4096,1024]
    float* out = (float*)d_out;

    char* ws = (char*)d_ws;
    _Float16* w1t  = (_Float16*)ws;                        // [0, 67108864)
    _Float16* xh   = (_Float16*)(ws + 67108864);           // [67108864, 75497472)
    _Float16* hbuf = (_Float16*)(ws + 75497472);           // [75497472, 142606336)
    char* p = ws + 142606336;                              // small arrays (<192 KB)
    int*   counts   = (int*)p;        p += 1024;
    int*   offs     = (int*)p;        p += 1024;
    int*   tmap256  = (int*)p;        p += 1024;
    int*   tmap128  = (int*)p;        p += 1024;
    int*   tok_e    = (int*)p;        p += NSLOT * 4;
    float* tok_w    = (float*)p;      p += NSLOT * 4;
    int*   tok_pos  = (int*)p;        p += NSLOT * 4;
    int*   tok_slot = (int*)p;        p += NSLOT * 4;
    int*   list_tok = (int*)p;        p += NSLOT * 4;
    const size_t OFF_EXT = 142606336 + 196608;             // 142,802,944
    const size_t SZ_Y  = (size_t)NSLOT * DIM * 2;          // 16,777,216 per split
    const size_t SZ_WT = (size_t)NE * DIM * FF * 2;        // 67,108,864

    // tier select (deterministic, by ws_size only)
    bool fused = (ws_size >= OFF_EXT + SZ_WT);             // 209,911,808: separate w2t

    hipMemsetAsync(counts, 0, 64, stream);
    // fused W1T + convert_x + router: 7 * 1024 blocks
    k_prep<<<7 * 1024, 256, 0, stream>>>(x, Wr, W1, w1t, xh,
                                         counts, tok_e, tok_w, tok_pos);
    k_prefix_slots<<<1, 256, 0, stream>>>(counts, offs, tmap256, tmap128,
                                          tok_e, tok_pos, tok_slot, list_tok);

    if (fused) {
        _Float16* w2t = (_Float16*)(ws + OFF_EXT);         // separate: concurrent with w1t
        _Float16* yp  = (_Float16*)ws;                     // overlays dead w1t (4*16.7MB <= 64MB)
        // FFN1 (128x128) + W2 transpose (128x64 swizzled tiles), interleaved blocks
        k_ffn1_fused<<<10 * 1152, 256, 0, stream>>>(
            xh, w1t, tmap128, counts, offs, list_tok, hbuf, W2, w2t);
        // FFN2: 256x256 split-K=4 partials into yp
        k_ffn256<FF, DIM, 1024, false, false>
            <<<dim3(NSLOT / 256 + NE, DIM / 256, 4), 512, 0, stream>>>(
                hbuf, w2t, tmap256, counts, offs, list_tok, yp);
        k_combine<<<NTOK, 256, 0, stream>>>(yp, tok_slot, tok_w, out, 4);
    } else {
        _Float16* w2t = w1t;                               // alias (sequential use)
        _Float16* yp  = (_Float16*)(ws + OFF_EXT);
        int nsplit = (ws_size >= OFF_EXT + 2 * SZ_Y) ? 2 : 1;
        k_ffn<DIM, FF, true, true>
            <<<dim3(NSLOT / 128 + NE, FF / 128), 256, 0, stream>>>(
                xh, w1t, tmap128, counts, offs, list_tok, hbuf);
        k_transpose<<<dim3(DIM / 64, FF / 64, NE), 256, 0, stream>>>(W2, w2t, FF, DIM);
        if (nsplit == 2) {
            k_ffn256<FF, DIM, 2048, false, false>
                <<<dim3(NSLOT / 256 + NE, DIM / 256, 2), 512, 0, stream>>>(
                    hbuf, w2t, tmap256, counts, offs, list_tok, yp);
        } else {
            k_ffn<FF, DIM, false, false>
                <<<dim3(NSLOT / 128 + NE, DIM / 128), 256, 0, stream>>>(
                    hbuf, w2t, tmap128, counts, offs, list_tok, yp);
        }
        k_combine<<<NTOK, 256, 0, stream>>>(yp, tok_slot, tok_w, out, nsplit);
    }
}